// Round 1
// baseline (1239.728 us; speedup 1.0000x reference)
//
#include <hip/hip_runtime.h>

// FeatureGradFetcher: B=2 V=5 C=16 H=512 W=640 N=131072
// out = concat(f (B,V,C,N), f_grad (B,V,C,N,2)) flat, float32.

namespace {
constexpr int Bc = 2, Vc = 5, Cc = 16, Hc = 512, Wc = 640;
constexpr int Nc = 131072;
constexpr int BVc = Bc * Vc;

__device__ __forceinline__ void axis_decomp(float t, int limit,
                                            int& i0, int& i1,
                                            float& w0, float& w1) {
    float f0 = floorf(t);
    float fr = t - f0;
    float f1 = f0 + 1.0f;
    float lim = (float)(limit - 1);
    // validity folded into weights (matches reference's per-corner valid mask:
    // corner_valid = valid_x & valid_y  ->  (wx*vx)*(wy*vy))
    w0 = (1.0f - fr) * ((f0 >= 0.0f && f0 <= lim) ? 1.0f : 0.0f);
    w1 = fr * ((f1 >= 0.0f && f1 <= lim) ? 1.0f : 0.0f);
    int i = (int)f0;
    i0 = min(max(i, 0), limit - 1);
    i1 = min(max(i + 1, 0), limit - 1);
}

__device__ __forceinline__ float bilin(const float* __restrict__ base,
                                       int x0, int x1, float wx0, float wx1,
                                       int y0, int y1, float wy0, float wy1) {
    const float* r0 = base + y0 * Wc;
    const float* r1 = base + y1 * Wc;
    return wy0 * (wx0 * r0[x0] + wx1 * r0[x1]) +
           wy1 * (wx0 * r1[x0] + wx1 * r1[x1]);
}

__global__ __launch_bounds__(256) void fgf_kernel(
    const float* __restrict__ fm,    // (BV, C, H, W)
    const float* __restrict__ pts,   // (B, 3, N)
    const float* __restrict__ Kmat,  // (BV, 3, 3)
    const float* __restrict__ Emat,  // (BV, 3, 4)
    float* __restrict__ out_f,       // (BV, C, N)
    float* __restrict__ out_g)       // (BV, C, N, 2)
{
    // 512 blocks per (bv, c); n fastest so bv/c are block-uniform -> s_loads for K/E.
    const int n   = ((int)(blockIdx.x & 511) << 8) | (int)threadIdx.x;
    const int bvc = (int)blockIdx.x >> 9;       // = bv*C + c
    const int bv  = bvc >> 4;
    const int b   = bv / Vc;

    const float px = pts[(b * 3 + 0) * Nc + n];
    const float py = pts[(b * 3 + 1) * Nc + n];
    const float pz = pts[(b * 3 + 2) * Nc + n];

    const float* E = Emat + bv * 12;
    const float xx = E[0] * px + E[1] * py + E[2]  * pz + E[3];
    const float yy = E[4] * px + E[5] * py + E[6]  * pz + E[7];
    const float zz = E[8] * px + E[9] * py + E[10] * pz + E[11];

    const float* K = Kmat + bv * 9;
    const float inv_z = 1.0f / zz;
    const float nx = xx * inv_z;
    const float ny = yy * inv_z;
    const float u = K[0] * nx + K[1] * ny + K[2];
    const float v = K[3] * nx + K[4] * ny + K[5];

    // gx = (u-0.5)/(W-1)*2 - 1 ; ix = ((gx+1)*W - 1)*0.5
    const float gx = (u - 0.5f) * (2.0f / (float)(Wc - 1)) - 1.0f;
    const float gy = (v - 0.5f) * (2.0f / (float)(Hc - 1)) - 1.0f;
    const float ix = ((gx + 1.0f) * (float)Wc - 1.0f) * 0.5f;
    const float iy = ((gy + 1.0f) * (float)Hc - 1.0f) * 0.5f;
    // grid-space shift dx=2/(W-1) maps to pixel-space shift W/(W-1)
    const float sx = (float)Wc / (float)(Wc - 1);
    const float sy = (float)Hc / (float)(Hc - 1);

    int xc0, xc1, xl0, xl1, xr0, xr1;
    int yc0, yc1, yt0, yt1, yb0, yb1;
    float wxc0, wxc1, wxl0, wxl1, wxr0, wxr1;
    float wyc0, wyc1, wyt0, wyt1, wyb0, wyb1;
    axis_decomp(ix,      Wc, xc0, xc1, wxc0, wxc1);
    axis_decomp(ix - sx, Wc, xl0, xl1, wxl0, wxl1);
    axis_decomp(ix + sx, Wc, xr0, xr1, wxr0, wxr1);
    axis_decomp(iy,      Hc, yc0, yc1, wyc0, wyc1);
    axis_decomp(iy - sy, Hc, yt0, yt1, wyt0, wyt1);
    axis_decomp(iy + sy, Hc, yb0, yb1, wyb0, wyb1);

    const float* base = fm + (size_t)bvc * (size_t)(Hc * Wc);

    const float fc = bilin(base, xc0, xc1, wxc0, wxc1, yc0, yc1, wyc0, wyc1);
    const float fl = bilin(base, xl0, xl1, wxl0, wxl1, yc0, yc1, wyc0, wyc1);
    const float fr = bilin(base, xr0, xr1, wxr0, wxr1, yc0, yc1, wyc0, wyc1);
    const float ft = bilin(base, xc0, xc1, wxc0, wxc1, yt0, yt1, wyt0, wyt1);
    const float fb = bilin(base, xc0, xc1, wxc0, wxc1, yb0, yb1, wyb0, wyb1);

    const int out_idx = (int)blockIdx.x * 256 + (int)threadIdx.x;  // = bvc*N + n
    out_f[out_idx] = fc;
    float2 g = make_float2(0.5f * (fr - fl), 0.5f * (fb - ft));
    *reinterpret_cast<float2*>(out_g + (size_t)out_idx * 2) = g;
}

}  // namespace

extern "C" void kernel_launch(void* const* d_in, const int* in_sizes, int n_in,
                              void* d_out, int out_size, void* d_ws, size_t ws_size,
                              hipStream_t stream) {
    const float* fm  = (const float*)d_in[0];
    const float* pts = (const float*)d_in[1];
    const float* K   = (const float*)d_in[2];
    const float* E   = (const float*)d_in[3];
    float* out_f = (float*)d_out;
    float* out_g = out_f + (size_t)BVc * Cc * Nc;
    const int blocks = BVc * Cc * (Nc / 256);  // 81920
    fgf_kernel<<<blocks, 256, 0, stream>>>(fm, pts, K, E, out_f, out_g);
}

// Round 2
// 1073.102 us; speedup vs baseline: 1.1553x; 1.1553x over previous
//
#include <hip/hip_runtime.h>

// FeatureGradFetcher: B=2 V=5 C=16 H=512 W=640 N=131072
// out = concat(f (B,V,C,N), f_grad (B,V,C,N,2)) flat, float32.
//
// R2 strategy: channels-last transpose of fm into d_ws so one tap = one 64B
// line = 4x dwordx4; one thread per (bv, n) covers all 16 channels.
// Cuts scattered lane-requests ~4x (the R1 bottleneck: 0.69 req/cy/CU at L1).

namespace {
constexpr int Bc = 2, Vc = 5, Cc = 16, Hc = 512, Wc = 640;
constexpr int Nc = 131072;
constexpr int BVc = Bc * Vc;
constexpr int HWc = Hc * Wc;
constexpr size_t FMT_BYTES = (size_t)BVc * HWc * Cc * sizeof(float);  // 209,715,200

__device__ __forceinline__ void axis_decomp(float t, int limit,
                                            int& i0, int& i1,
                                            float& w0, float& w1) {
    float f0 = floorf(t);
    float fr = t - f0;
    float f1 = f0 + 1.0f;
    float lim = (float)(limit - 1);
    w0 = (1.0f - fr) * ((f0 >= 0.0f && f0 <= lim) ? 1.0f : 0.0f);
    w1 = fr * ((f1 >= 0.0f && f1 <= lim) ? 1.0f : 0.0f);
    int i = (int)f0;
    i0 = min(max(i, 0), limit - 1);
    i1 = min(max(i + 1, 0), limit - 1);
}

// ---- fm (BV,C,H,W) -> fmt (BV,H,W,C) ----
__global__ __launch_bounds__(256) void transpose_kernel(
    const float* __restrict__ fm, float* __restrict__ fmt) {
    __shared__ float lds[16 * 256];
    const int blocks_per_bv = HWc / 256;  // 1280
    const int bv = (int)blockIdx.x / blocks_per_bv;
    const int pix0 = ((int)blockIdx.x % blocks_per_bv) * 256;
    const int t = (int)threadIdx.x;
#pragma unroll
    for (int c = 0; c < 16; ++c) {
        // coalesced read; LDS write bank = t%32, conflict-free
        lds[c * 256 + t] = fm[(size_t)(bv * 16 + c) * HWc + pix0 + t];
    }
    __syncthreads();
    float4* dst = reinterpret_cast<float4*>(fmt + (size_t)(bv * HWc + pix0 + t) * 16);
#pragma unroll
    for (int j = 0; j < 4; ++j) {
        float4 v;
        v.x = lds[(4 * j + 0) * 256 + t];
        v.y = lds[(4 * j + 1) * 256 + t];
        v.z = lds[(4 * j + 2) * 256 + t];
        v.w = lds[(4 * j + 3) * 256 + t];
        dst[j] = v;  // lane t owns pixel t's full 64B line
    }
}

// ---- gather: one thread per (bv, n), all 16 channels ----
__global__ __launch_bounds__(256) void gather_kernel(
    const float* __restrict__ fmt,   // (BV, H, W, C)
    const float* __restrict__ pts,   // (B, 3, N)
    const float* __restrict__ Kmat,  // (BV, 3, 3)
    const float* __restrict__ Emat,  // (BV, 3, 4)
    float* __restrict__ out_f,       // (BV, C, N)
    float* __restrict__ out_g)       // (BV, C, N, 2)
{
    const int n  = (((int)blockIdx.x & 511) << 8) | (int)threadIdx.x;
    const int bv = (int)blockIdx.x >> 9;
    const int b  = bv / Vc;

    const float px = pts[(b * 3 + 0) * Nc + n];
    const float py = pts[(b * 3 + 1) * Nc + n];
    const float pz = pts[(b * 3 + 2) * Nc + n];

    const float* E = Emat + bv * 12;
    const float xx = E[0] * px + E[1] * py + E[2]  * pz + E[3];
    const float yy = E[4] * px + E[5] * py + E[6]  * pz + E[7];
    const float zz = E[8] * px + E[9] * py + E[10] * pz + E[11];

    const float* K = Kmat + bv * 9;
    const float inv_z = 1.0f / zz;
    const float nx = xx * inv_z;
    const float ny = yy * inv_z;
    const float u = K[0] * nx + K[1] * ny + K[2];
    const float v = K[3] * nx + K[4] * ny + K[5];

    const float gx = (u - 0.5f) * (2.0f / (float)(Wc - 1)) - 1.0f;
    const float gy = (v - 0.5f) * (2.0f / (float)(Hc - 1)) - 1.0f;
    const float ix = ((gx + 1.0f) * (float)Wc - 1.0f) * 0.5f;
    const float iy = ((gy + 1.0f) * (float)Hc - 1.0f) * 0.5f;
    const float sx = (float)Wc / (float)(Wc - 1);  // grid dx in pixel space
    const float sy = (float)Hc / (float)(Hc - 1);

    int xc0, xc1, xl0, xl1, xr0, xr1;
    int yc0, yc1, yt0, yt1, yb0, yb1;
    float wxc0, wxc1, wxl0, wxl1, wxr0, wxr1;
    float wyc0, wyc1, wyt0, wyt1, wyb0, wyb1;
    axis_decomp(ix,      Wc, xc0, xc1, wxc0, wxc1);
    axis_decomp(ix - sx, Wc, xl0, xl1, wxl0, wxl1);
    axis_decomp(ix + sx, Wc, xr0, xr1, wxr0, wxr1);
    axis_decomp(iy,      Hc, yc0, yc1, wyc0, wyc1);
    axis_decomp(iy - sy, Hc, yt0, yt1, wyt0, wyt1);
    axis_decomp(iy + sy, Hc, yb0, yb1, wyb0, wyb1);

    float4 accF[4], accGx[4], accGy[4];
#pragma unroll
    for (int j = 0; j < 4; ++j) {
        accF[j]  = make_float4(0.f, 0.f, 0.f, 0.f);
        accGx[j] = make_float4(0.f, 0.f, 0.f, 0.f);
        accGy[j] = make_float4(0.f, 0.f, 0.f, 0.f);
    }

    const float* plane = fmt + (size_t)bv * HWc * 16;

    auto tap = [&](int x, int y, float w, float4* acc) {
        const float4* p = reinterpret_cast<const float4*>(plane + (size_t)(y * Wc + x) * 16);
#pragma unroll
        for (int j = 0; j < 4; ++j) {
            float4 vv = p[j];
            acc[j].x += w * vv.x;
            acc[j].y += w * vv.y;
            acc[j].z += w * vv.z;
            acc[j].w += w * vv.w;
        }
    };
    auto sample = [&](int x0, int x1, float wx0, float wx1,
                      int y0, int y1, float wy0, float wy1,
                      float4* acc, float s) {
        tap(x0, y0, s * wx0 * wy0, acc);
        tap(x1, y0, s * wx1 * wy0, acc);
        tap(x0, y1, s * wx0 * wy1, acc);
        tap(x1, y1, s * wx1 * wy1, acc);
    };

    sample(xc0, xc1, wxc0, wxc1, yc0, yc1, wyc0, wyc1, accF,  1.0f);
    sample(xl0, xl1, wxl0, wxl1, yc0, yc1, wyc0, wyc1, accGx, -0.5f);
    sample(xr0, xr1, wxr0, wxr1, yc0, yc1, wyc0, wyc1, accGx,  0.5f);
    sample(xc0, xc1, wxc0, wxc1, yt0, yt1, wyt0, wyt1, accGy, -0.5f);
    sample(xc0, xc1, wxc0, wxc1, yb0, yb1, wyb0, wyb1, accGy,  0.5f);

#pragma unroll
    for (int j = 0; j < 4; ++j) {
        float fs[4]  = {accF[j].x,  accF[j].y,  accF[j].z,  accF[j].w};
        float gxs[4] = {accGx[j].x, accGx[j].y, accGx[j].z, accGx[j].w};
        float gys[4] = {accGy[j].x, accGy[j].y, accGy[j].z, accGy[j].w};
#pragma unroll
        for (int k = 0; k < 4; ++k) {
            const int c = 4 * j + k;
            const size_t o = (size_t)(bv * 16 + c) * Nc + n;
            out_f[o] = fs[k];
            *reinterpret_cast<float2*>(out_g + 2 * o) = make_float2(gxs[k], gys[k]);
        }
    }
}

// ---- R1 fallback (thread per (bv,c,n), direct from (BV,C,H,W)) ----
__device__ __forceinline__ float bilin(const float* __restrict__ base,
                                       int x0, int x1, float wx0, float wx1,
                                       int y0, int y1, float wy0, float wy1) {
    const float* r0 = base + y0 * Wc;
    const float* r1 = base + y1 * Wc;
    return wy0 * (wx0 * r0[x0] + wx1 * r0[x1]) +
           wy1 * (wx0 * r1[x0] + wx1 * r1[x1]);
}

__global__ __launch_bounds__(256) void fgf_fallback_kernel(
    const float* __restrict__ fm, const float* __restrict__ pts,
    const float* __restrict__ Kmat, const float* __restrict__ Emat,
    float* __restrict__ out_f, float* __restrict__ out_g) {
    const int n   = (((int)blockIdx.x & 511) << 8) | (int)threadIdx.x;
    const int bvc = (int)blockIdx.x >> 9;
    const int bv  = bvc >> 4;
    const int b   = bv / Vc;

    const float px = pts[(b * 3 + 0) * Nc + n];
    const float py = pts[(b * 3 + 1) * Nc + n];
    const float pz = pts[(b * 3 + 2) * Nc + n];
    const float* E = Emat + bv * 12;
    const float xx = E[0] * px + E[1] * py + E[2]  * pz + E[3];
    const float yy = E[4] * px + E[5] * py + E[6]  * pz + E[7];
    const float zz = E[8] * px + E[9] * py + E[10] * pz + E[11];
    const float* K = Kmat + bv * 9;
    const float inv_z = 1.0f / zz;
    const float u = K[0] * (xx * inv_z) + K[1] * (yy * inv_z) + K[2];
    const float v = K[3] * (xx * inv_z) + K[4] * (yy * inv_z) + K[5];
    const float gx = (u - 0.5f) * (2.0f / (float)(Wc - 1)) - 1.0f;
    const float gy = (v - 0.5f) * (2.0f / (float)(Hc - 1)) - 1.0f;
    const float ix = ((gx + 1.0f) * (float)Wc - 1.0f) * 0.5f;
    const float iy = ((gy + 1.0f) * (float)Hc - 1.0f) * 0.5f;
    const float sx = (float)Wc / (float)(Wc - 1);
    const float sy = (float)Hc / (float)(Hc - 1);

    int xc0, xc1, xl0, xl1, xr0, xr1, yc0, yc1, yt0, yt1, yb0, yb1;
    float wxc0, wxc1, wxl0, wxl1, wxr0, wxr1, wyc0, wyc1, wyt0, wyt1, wyb0, wyb1;
    axis_decomp(ix,      Wc, xc0, xc1, wxc0, wxc1);
    axis_decomp(ix - sx, Wc, xl0, xl1, wxl0, wxl1);
    axis_decomp(ix + sx, Wc, xr0, xr1, wxr0, wxr1);
    axis_decomp(iy,      Hc, yc0, yc1, wyc0, wyc1);
    axis_decomp(iy - sy, Hc, yt0, yt1, wyt0, wyt1);
    axis_decomp(iy + sy, Hc, yb0, yb1, wyb0, wyb1);

    const float* base = fm + (size_t)bvc * HWc;
    const float fc = bilin(base, xc0, xc1, wxc0, wxc1, yc0, yc1, wyc0, wyc1);
    const float fl = bilin(base, xl0, xl1, wxl0, wxl1, yc0, yc1, wyc0, wyc1);
    const float fr = bilin(base, xr0, xr1, wxr0, wxr1, yc0, yc1, wyc0, wyc1);
    const float ft = bilin(base, xc0, xc1, wxc0, wxc1, yt0, yt1, wyt0, wyt1);
    const float fb = bilin(base, xc0, xc1, wxc0, wxc1, yb0, yb1, wyb0, wyb1);

    const size_t out_idx = (size_t)blockIdx.x * 256 + threadIdx.x;
    out_f[out_idx] = fc;
    *reinterpret_cast<float2*>(out_g + out_idx * 2) =
        make_float2(0.5f * (fr - fl), 0.5f * (fb - ft));
}

}  // namespace

extern "C" void kernel_launch(void* const* d_in, const int* in_sizes, int n_in,
                              void* d_out, int out_size, void* d_ws, size_t ws_size,
                              hipStream_t stream) {
    const float* fm  = (const float*)d_in[0];
    const float* pts = (const float*)d_in[1];
    const float* K   = (const float*)d_in[2];
    const float* E   = (const float*)d_in[3];
    float* out_f = (float*)d_out;
    float* out_g = out_f + (size_t)BVc * Cc * Nc;

    if (ws_size >= FMT_BYTES) {
        float* fmt = (float*)d_ws;
        transpose_kernel<<<BVc * (HWc / 256), 256, 0, stream>>>(fm, fmt);
        gather_kernel<<<BVc * (Nc / 256), 256, 0, stream>>>(fmt, pts, K, E, out_f, out_g);
    } else {
        fgf_fallback_kernel<<<BVc * Cc * (Nc / 256), 256, 0, stream>>>(
            fm, pts, K, E, out_f, out_g);
    }
}